// Round 2
// baseline (299.955 us; speedup 1.0000x reference)
//
#include <hip/hip_runtime.h>

// Problem constants (fixed by setup_inputs)
#define B_   8
#define NN   2000
#define EE   20
#define HH   128
#define BN   (B_*NN)      // 16000 rows of x
#define NE   (NN*EE)      // 40000 e-rows per batch

typedef unsigned short ushort_t;
typedef __bf16 bf16x8 __attribute__((ext_vector_type(8)));
typedef float  f32x4  __attribute__((ext_vector_type(4)));
typedef float  f4     __attribute__((ext_vector_type(4)));
typedef unsigned short us8 __attribute__((ext_vector_type(8)));
typedef unsigned short us4 __attribute__((ext_vector_type(4)));

union FragU { us8 u; bf16x8 b; };

__device__ __forceinline__ float b2f(ushort_t v) {
    union { unsigned int i; float f; } c; c.i = ((unsigned int)v) << 16; return c.f;
}
__device__ __forceinline__ ushort_t f2b(float f) {   // RNE fp32 -> bf16
    union { float f; unsigned int i; } c; c.f = f;
    unsigned int r = (c.i + 0x7FFFu + ((c.i >> 16) & 1u)) >> 16;
    return (ushort_t)r;
}

// ---------------------------------------------------------------------------
// K1: Uxb = bf16(x@Wu + bu), Vxb = bf16(x@Wv + bv)   (both -> ws)
// grid (125, 2): y=0 -> Wu/Uxb, y=1 -> Wv/Vxb. Block = 128 rows, 4 waves (2x2).
// ---------------------------------------------------------------------------
__global__ __launch_bounds__(256, 2) void k1_embed(
    const float* __restrict__ x,
    const float* __restrict__ Wu, const float* __restrict__ bu,
    const float* __restrict__ Wv, const float* __restrict__ bv,
    ushort_t* __restrict__ Uxb, ushort_t* __restrict__ Vxb)
{
    __shared__ __align__(16) ushort_t As[128 * 136];  // bf16 tile, padded stride

    const int tid  = threadIdx.x;
    const int lane = tid & 63;
    const int wave = tid >> 6;
    const int wm = wave >> 1, wn = wave & 1;   // 2x2 wave grid
    const int q  = lane >> 4, ln = lane & 15;
    const int m0 = blockIdx.x * 128;
    const int sel = blockIdx.y;
    const float* W    = sel ? Wv : Wu;
    const float* bias = sel ? bv : bu;
    ushort_t* dst = sel ? Vxb : Uxb;

    // stage A tile: fp32 -> bf16 into padded LDS. 128 rows x 32 chunks of 4.
    for (int c = tid; c < 128 * 32; c += 256) {
        int row = c >> 5, col = (c & 31) * 4;
        f4 v = *(const f4*)(x + (size_t)(m0 + row) * HH + col);
        us4 pk;
#pragma unroll
        for (int r = 0; r < 4; ++r) pk[r] = f2b(v[r]);
        *(us4*)(&As[row * 136 + col]) = pk;
    }

    // B fragments in registers (fp32 loads, cvt to bf16)
    FragU bf[4][4];  // [ki][tn]
#pragma unroll
    for (int ki = 0; ki < 4; ++ki)
#pragma unroll
        for (int tn = 0; tn < 4; ++tn) {
            int n = wn * 64 + tn * 16 + ln;
            us8 tmp;
#pragma unroll
            for (int i = 0; i < 8; ++i) tmp[i] = f2b(W[(ki * 32 + q * 8 + i) * HH + n]);
            bf[ki][tn].u = tmp;
        }

    f32x4 acc[4][4];
#pragma unroll
    for (int tm = 0; tm < 4; ++tm)
#pragma unroll
        for (int tn = 0; tn < 4; ++tn) acc[tm][tn] = (f32x4){0.f, 0.f, 0.f, 0.f};

    __syncthreads();

#pragma unroll
    for (int ki = 0; ki < 4; ++ki) {
        FragU af[4];
#pragma unroll
        for (int tm = 0; tm < 4; ++tm) {
            int row = wm * 64 + tm * 16 + ln;
            af[tm].u = *(const us8*)(&As[row * 136 + ki * 32 + q * 8]);
        }
#pragma unroll
        for (int tm = 0; tm < 4; ++tm)
#pragma unroll
            for (int tn = 0; tn < 4; ++tn)
                acc[tm][tn] = __builtin_amdgcn_mfma_f32_16x16x32_bf16(
                    af[tm].b, bf[ki][tn].b, acc[tm][tn], 0, 0, 0);
    }

    // epilogue: D layout col=lane&15, row=(lane>>4)*4+reg
#pragma unroll
    for (int tn = 0; tn < 4; ++tn) {
        int col = wn * 64 + tn * 16 + ln;
        float bb = bias[col];
#pragma unroll
        for (int tm = 0; tm < 4; ++tm) {
            int rowb = m0 + wm * 64 + tm * 16 + q * 4;
#pragma unroll
            for (int r = 0; r < 4; ++r) {
                float v = acc[tm][tn][r] + bb;
                dst[(size_t)(rowb + r) * HH + col] = f2b(v);
            }
        }
    }
}

// ---------------------------------------------------------------------------
// K2: per block = 8 nodes (160 contiguous e-rows).
//   logits = e@We (MFMA bf16) -> LDS column-major -> softmax over E=20
//   -> gather Vxb[edge_index] -> weighted sum -> + Uxb -> out (fp32)
// Note: be cancels in softmax (constant over the E axis) -> skipped.
// ---------------------------------------------------------------------------
__global__ __launch_bounds__(256, 2) void k2_fused(
    const float* __restrict__ e, const float* __restrict__ We,
    const int* __restrict__ eidx,
    const ushort_t* __restrict__ Uxb, const ushort_t* __restrict__ Vxb,
    float* __restrict__ out)
{
    // As: 160x136 bf16 (43520B). After MFMA, aliased as CT[128][168] bf16 (43008B).
    __shared__ __align__(16) ushort_t smem[160 * 136];
    __shared__ int sidx[160];

    const int tid  = threadIdx.x;
    const int lane = tid & 63;
    const int wave = tid >> 6;
    const int wm = wave >> 1, wn = wave & 1;   // wave: M=80 (5 tiles) x N=64 (4 tiles)
    const int q  = lane >> 4, ln = lane & 15;

    const int node0 = blockIdx.x * 8;          // global node id of first node
    const int b   = node0 / NN;
    const int nl0 = node0 - b * NN;            // 2000 % 8 == 0: no batch straddle
    const size_t erow0 = (size_t)b * NE + (size_t)nl0 * EE;

    // stage A: 160 e-rows, fp32 -> bf16, into padded LDS
    for (int c = tid; c < 160 * 32; c += 256) {
        int row = c >> 5, col = (c & 31) * 4;
        f4 v = *(const f4*)(e + (erow0 + row) * HH + col);
        us4 pk;
#pragma unroll
        for (int r = 0; r < 4; ++r) pk[r] = f2b(v[r]);
        *(us4*)(&smem[row * 136 + col]) = pk;
    }
    if (tid < 160) sidx[tid] = eidx[erow0 + tid];

    // B fragments (We) in registers
    FragU bf[4][4];
#pragma unroll
    for (int ki = 0; ki < 4; ++ki)
#pragma unroll
        for (int tn = 0; tn < 4; ++tn) {
            int n = wn * 64 + tn * 16 + ln;
            us8 tmp;
#pragma unroll
            for (int i = 0; i < 8; ++i) tmp[i] = f2b(We[(ki * 32 + q * 8 + i) * HH + n]);
            bf[ki][tn].u = tmp;
        }

    f32x4 acc[5][4];
#pragma unroll
    for (int tm = 0; tm < 5; ++tm)
#pragma unroll
        for (int tn = 0; tn < 4; ++tn) acc[tm][tn] = (f32x4){0.f, 0.f, 0.f, 0.f};

    __syncthreads();

#pragma unroll
    for (int ki = 0; ki < 4; ++ki) {
        FragU af[5];
#pragma unroll
        for (int tm = 0; tm < 5; ++tm) {
            int row = wm * 80 + tm * 16 + ln;
            af[tm].u = *(const us8*)(&smem[row * 136 + ki * 32 + q * 8]);
        }
#pragma unroll
        for (int tm = 0; tm < 5; ++tm)
#pragma unroll
            for (int tn = 0; tn < 4; ++tn)
                acc[tm][tn] = __builtin_amdgcn_mfma_f32_16x16x32_bf16(
                    af[tm].b, bf[ki][tn].b, acc[tm][tn], 0, 0, 0);
    }

    __syncthreads();  // all A reads done; smem now reused as CT

    // write C transposed: CT[col][row] bf16, stride 168. Lane's 4 regs = 4
    // consecutive rows, same col -> one 8B store.
#pragma unroll
    for (int tm = 0; tm < 5; ++tm)
#pragma unroll
        for (int tn = 0; tn < 4; ++tn) {
            int col  = wn * 64 + tn * 16 + ln;
            int rowb = wm * 80 + tm * 16 + q * 4;
            us4 pk;
#pragma unroll
            for (int r = 0; r < 4; ++r) pk[r] = f2b(acc[tm][tn][r]);
            *(us4*)(&smem[col * 168 + rowb]) = pk;
        }

    __syncthreads();

    // epilogue: 1024 (g,h) items over 256 threads
    const int h  = tid & 127;
    const int gp = tid >> 7;
#pragma unroll 1
    for (int j = 0; j < 4; ++j) {
        int g = gp + 2 * j;
        const ushort_t* ctp = &smem[h * 168 + g * 20];
        float lv[20];
#pragma unroll
        for (int i = 0; i < 5; ++i) {
            us4 v = *(const us4*)(ctp + i * 4);
#pragma unroll
            for (int r = 0; r < 4; ++r) lv[i * 4 + r] = b2f(v[r]);
        }
        float mx = lv[0];
#pragma unroll
        for (int k = 1; k < EE; ++k) mx = fmaxf(mx, lv[k]);

        // gather neighbor Vx values (coalesced: 128 lanes x 2B per k)
        ushort_t gv[20];
        const int ib = g * 20;
#pragma unroll
        for (int k = 0; k < EE; ++k)
            gv[k] = Vxb[(size_t)(b * NN + sidx[ib + k]) * HH + h];

        float s = 0.f, a = 0.f;
#pragma unroll
        for (int k = 0; k < EE; ++k) {
            float p = __expf(lv[k] - mx);
            s += p;
            a = fmaf(p, b2f(gv[k]), a);
        }
        size_t orow = (size_t)(node0 + g) * HH + h;
        out[orow] = b2f(Uxb[orow]) + a / s;
    }
}

// ---------------------------------------------------------------------------
extern "C" void kernel_launch(void* const* d_in, const int* in_sizes, int n_in,
                              void* d_out, int out_size, void* d_ws, size_t ws_size,
                              hipStream_t stream) {
    const float* x  = (const float*)d_in[0];
    const float* e  = (const float*)d_in[1];
    const float* Wu = (const float*)d_in[2];
    const float* bu = (const float*)d_in[3];
    const float* Wv = (const float*)d_in[4];
    const float* bv = (const float*)d_in[5];
    const float* We = (const float*)d_in[6];
    // d_in[7] = be: cancels in softmax, unused
    const int*   eidx = (const int*)d_in[8];
    // d_in[9] = n_edges (=20), compiled in

    ushort_t* Uxb = (ushort_t*)d_ws;                                   // 16000*128 bf16 = 4.096 MB
    ushort_t* Vxb = (ushort_t*)((char*)d_ws + (size_t)BN * HH * 2);    // 16000*128 bf16 = 4.096 MB
    float*    o   = (float*)d_out;

    k1_embed<<<dim3(125, 2), 256, 0, stream>>>(x, Wu, bu, Wv, bv, Uxb, Vxb);
    k2_fused<<<dim3(2000), 256, 0, stream>>>(e, We, eidx, Uxb, Vxb, o);
}

// Round 3
// 275.707 us; speedup vs baseline: 1.0879x; 1.0879x over previous
//
#include <hip/hip_runtime.h>

// Problem constants (fixed by setup_inputs)
#define B_   8
#define NN   2000
#define EE   20
#define HH   128
#define BN   (B_*NN)      // 16000 rows of x
#define NE   (NN*EE)      // 40000 e-rows per batch

typedef unsigned short ushort_t;
typedef __bf16 bf16x8 __attribute__((ext_vector_type(8)));
typedef float  f32x4  __attribute__((ext_vector_type(4)));
typedef float  f4     __attribute__((ext_vector_type(4)));
typedef unsigned short us8 __attribute__((ext_vector_type(8)));
typedef unsigned short us4 __attribute__((ext_vector_type(4)));

union FragU { us8 u; bf16x8 b; };

__device__ __forceinline__ float b2f(ushort_t v) {
    union { unsigned int i; float f; } c; c.i = ((unsigned int)v) << 16; return c.f;
}
__device__ __forceinline__ ushort_t f2b(float f) {   // RNE fp32 -> bf16
    union { float f; unsigned int i; } c; c.f = f;
    unsigned int r = (c.i + 0x7FFFu + ((c.i >> 16) & 1u)) >> 16;
    return (ushort_t)r;
}

// ---------------------------------------------------------------------------
// K1: Uxb = bf16(x@Wu + bu), Vxb = bf16(x@Wv + bv)   (both -> ws)
// Barrier-free: A fragments loaded directly from global (coalesced), no LDS.
// grid (250, 2): x = 64-row tile, y = {Wu, Wv}. 4 waves (wm x wn = 2x2).
// ---------------------------------------------------------------------------
__global__ __launch_bounds__(256) void k1_embed(
    const float* __restrict__ x,
    const float* __restrict__ Wu, const float* __restrict__ bu,
    const float* __restrict__ Wv, const float* __restrict__ bv,
    ushort_t* __restrict__ Uxb, ushort_t* __restrict__ Vxb)
{
    const int tid  = threadIdx.x;
    const int lane = tid & 63;
    const int wave = tid >> 6;
    const int wm = wave >> 1, wn = wave & 1;
    const int q  = lane >> 4, ln = lane & 15;
    const int m0 = blockIdx.x * 64;
    const int sel = blockIdx.y;
    const float* W    = sel ? Wv : Wu;
    const float* bias = sel ? bv : bu;
    ushort_t* dst = sel ? Vxb : Uxb;

    // A fragments direct from global: lane (ln,q) reads 8 contiguous fp32 of
    // row m0+wm*32+tm*16+ln at col ki*32+q*8 -> fully coalesced per wave.
    FragU af[2][4];  // [tm][ki]
#pragma unroll
    for (int tm = 0; tm < 2; ++tm)
#pragma unroll
        for (int ki = 0; ki < 4; ++ki) {
            const float* p = x + (size_t)(m0 + wm * 32 + tm * 16 + ln) * HH + ki * 32 + q * 8;
            f4 lo = *(const f4*)(p);
            f4 hi = *(const f4*)(p + 4);
            us8 t;
#pragma unroll
            for (int r = 0; r < 4; ++r) { t[r] = f2b(lo[r]); t[r + 4] = f2b(hi[r]); }
            af[tm][ki].u = t;
        }

    // B fragments: lane holds W[k=ki*32+q*8+i][n] (L2-hot, 64KB)
    FragU bf[4][4];  // [ki][tn]
#pragma unroll
    for (int ki = 0; ki < 4; ++ki)
#pragma unroll
        for (int tn = 0; tn < 4; ++tn) {
            int n = wn * 64 + tn * 16 + ln;
            us8 t;
#pragma unroll
            for (int i = 0; i < 8; ++i) t[i] = f2b(W[(ki * 32 + q * 8 + i) * HH + n]);
            bf[ki][tn].u = t;
        }

    f32x4 acc[2][4];
#pragma unroll
    for (int tm = 0; tm < 2; ++tm)
#pragma unroll
        for (int tn = 0; tn < 4; ++tn) acc[tm][tn] = (f32x4){0.f, 0.f, 0.f, 0.f};

#pragma unroll
    for (int ki = 0; ki < 4; ++ki)
#pragma unroll
        for (int tm = 0; tm < 2; ++tm)
#pragma unroll
            for (int tn = 0; tn < 4; ++tn)
                acc[tm][tn] = __builtin_amdgcn_mfma_f32_16x16x32_bf16(
                    af[tm][ki].b, bf[ki][tn].b, acc[tm][tn], 0, 0, 0);

    // D layout: col=lane&15, row=(lane>>4)*4+reg
#pragma unroll
    for (int tn = 0; tn < 4; ++tn) {
        int col = wn * 64 + tn * 16 + ln;
        float bb = bias[col];
#pragma unroll
        for (int tm = 0; tm < 2; ++tm) {
            int rowb = m0 + wm * 32 + tm * 16 + q * 4;
#pragma unroll
            for (int r = 0; r < 4; ++r)
                dst[(size_t)(rowb + r) * HH + col] = f2b(acc[tm][tn][r] + bb);
        }
    }
}

// ---------------------------------------------------------------------------
// K2: per block = 4 nodes (80 contiguous e-rows), grid (500, 8).
//   logits = e@We (MFMA bf16, A staged via LDS) -> CT in LDS column-major
//   -> softmax over E=20 -> gather Vxb -> weighted sum -> + Uxb -> out fp32
// be cancels in softmax -> skipped.
// 4 waves, each: all 5 m-tiles x 2 n-tiles (wave owns 32 cols).
// ---------------------------------------------------------------------------
#define ASTR 136   // A tile LDS stride (ushorts): 68 dwords, conflict-minimal
#define CSTR 84    // CT stride (ushorts): 42 dwords (gcd 2 w/32) -> ~4-way max

__global__ __launch_bounds__(256, 4) void k2_fused(
    const float* __restrict__ e, const float* __restrict__ We,
    const int* __restrict__ eidx,
    const ushort_t* __restrict__ Uxb, const ushort_t* __restrict__ Vxb,
    float* __restrict__ out)
{
    // A: 80 x ASTR = 10880 us; CT: 128 x CSTR = 10752 us. Aliased.
    __shared__ __align__(16) ushort_t smem[11008];
    __shared__ int sidx[80];

    const int tid  = threadIdx.x;
    const int lane = tid & 63;
    const int wave = tid >> 6;            // owns cols [wave*32, wave*32+32)
    const int q  = lane >> 4, ln = lane & 15;

    const int b   = blockIdx.y;
    const int nl0 = blockIdx.x * 4;       // first node (local)
    const size_t erow0 = (size_t)b * NE + (size_t)nl0 * EE;  // 80 rows

    // stage A: 80 e-rows fp32 -> bf16 into LDS (10 f4 loads/thread, independent)
    for (int c = tid; c < 80 * 32; c += 256) {
        int row = c >> 5, col = (c & 31) * 4;
        f4 v = *(const f4*)(e + (erow0 + row) * HH + col);
        us4 pk;
#pragma unroll
        for (int r = 0; r < 4; ++r) pk[r] = f2b(v[r]);
        *(us4*)(&smem[row * ASTR + col]) = pk;
    }
    if (tid < 80) sidx[tid] = eidx[erow0 + tid];

    // B fragments (We, L2-hot)
    FragU bf[4][2];  // [ki][tn]
#pragma unroll
    for (int ki = 0; ki < 4; ++ki)
#pragma unroll
        for (int tn = 0; tn < 2; ++tn) {
            int n = wave * 32 + tn * 16 + ln;
            us8 t;
#pragma unroll
            for (int i = 0; i < 8; ++i) t[i] = f2b(We[(ki * 32 + q * 8 + i) * HH + n]);
            bf[ki][tn].u = t;
        }

    f32x4 acc[5][2];
#pragma unroll
    for (int tm = 0; tm < 5; ++tm)
#pragma unroll
        for (int tn = 0; tn < 2; ++tn) acc[tm][tn] = (f32x4){0.f, 0.f, 0.f, 0.f};

    __syncthreads();

#pragma unroll
    for (int ki = 0; ki < 4; ++ki) {
        FragU af[5];
#pragma unroll
        for (int tm = 0; tm < 5; ++tm)
            af[tm].u = *(const us8*)(&smem[(tm * 16 + ln) * ASTR + ki * 32 + q * 8]);
#pragma unroll
        for (int tm = 0; tm < 5; ++tm)
#pragma unroll
            for (int tn = 0; tn < 2; ++tn)
                acc[tm][tn] = __builtin_amdgcn_mfma_f32_16x16x32_bf16(
                    af[tm].b, bf[ki][tn].b, acc[tm][tn], 0, 0, 0);
    }

    __syncthreads();  // A reads done; smem becomes CT

    // CT[col][row] bf16: lane's 4 regs = 4 consecutive rows -> one us4 store
#pragma unroll
    for (int tm = 0; tm < 5; ++tm)
#pragma unroll
        for (int tn = 0; tn < 2; ++tn) {
            int col  = wave * 32 + tn * 16 + ln;
            int rowb = tm * 16 + q * 4;
            us4 pk;
#pragma unroll
            for (int r = 0; r < 4; ++r) pk[r] = f2b(acc[tm][tn][r]);
            *(us4*)(&smem[col * CSTR + rowb]) = pk;
        }

    __syncthreads();

    // epilogue: 512 (g,h) items over 256 threads -> 2 each
    const int h  = tid & 127;
    const int gp = tid >> 7;
#pragma unroll 1
    for (int j = 0; j < 2; ++j) {
        int g = gp + 2 * j;
        const ushort_t* ctp = &smem[h * CSTR + g * 20];
        float lv[20];
#pragma unroll
        for (int i = 0; i < 5; ++i) {
            us4 v = *(const us4*)(ctp + i * 4);
#pragma unroll
            for (int r = 0; r < 4; ++r) lv[i * 4 + r] = b2f(v[r]);
        }
        float mx = lv[0];
#pragma unroll
        for (int k = 1; k < EE; ++k) mx = fmaxf(mx, lv[k]);

        // gather neighbor Vxb (per k: 128 lanes x 2B contiguous)
        ushort_t gv[20];
        const int ib = g * 20;
#pragma unroll
        for (int k = 0; k < EE; ++k)
            gv[k] = Vxb[(size_t)(b * NN + sidx[ib + k]) * HH + h];

        float s = 0.f, a = 0.f;
#pragma unroll
        for (int k = 0; k < EE; ++k) {
            float p = __expf(lv[k] - mx);
            s += p;
            a = fmaf(p, b2f(gv[k]), a);
        }
        size_t orow = (size_t)(b * NN + nl0 + g) * HH + h;
        out[orow] = b2f(Uxb[orow]) + a / s;
    }
}

// ---------------------------------------------------------------------------
extern "C" void kernel_launch(void* const* d_in, const int* in_sizes, int n_in,
                              void* d_out, int out_size, void* d_ws, size_t ws_size,
                              hipStream_t stream) {
    const float* x  = (const float*)d_in[0];
    const float* e  = (const float*)d_in[1];
    const float* Wu = (const float*)d_in[2];
    const float* bu = (const float*)d_in[3];
    const float* Wv = (const float*)d_in[4];
    const float* bv = (const float*)d_in[5];
    const float* We = (const float*)d_in[6];
    // d_in[7] = be: cancels in softmax, unused
    const int*   eidx = (const int*)d_in[8];
    // d_in[9] = n_edges (=20), compiled in

    ushort_t* Uxb = (ushort_t*)d_ws;                                   // 4.096 MB
    ushort_t* Vxb = (ushort_t*)((char*)d_ws + (size_t)BN * HH * 2);    // 4.096 MB
    float*    o   = (float*)d_out;

    k1_embed<<<dim3(250, 2), 256, 0, stream>>>(x, Wu, bu, Wv, bv, Uxb, Vxb);
    k2_fused<<<dim3(500, 8), 256, 0, stream>>>(e, We, eidx, Uxb, Vxb, o);
}